// Round 7
// baseline (472.022 us; speedup 1.0000x reference)
//
#include <hip/hip_runtime.h>

#define EOT_ID 50256

typedef __attribute__((ext_vector_type(8))) short bf16x8;
typedef __attribute__((ext_vector_type(4))) float f32x4;
typedef __attribute__((ext_vector_type(4))) unsigned short u16x4;

#define GLOAD_LDS(g, l)                                                        \
  __builtin_amdgcn_global_load_lds(                                            \
      (const __attribute__((address_space(1))) unsigned int*)(g),              \
      (__attribute__((address_space(3))) unsigned int*)(l), 16, 0, 0)

__device__ __forceinline__ unsigned short f2bf(float f) {
  union { float f; unsigned int u; } v; v.f = f;
  unsigned int r = v.u + 0x7FFFu + ((v.u >> 16) & 1u);
  return (unsigned short)(r >> 16);
}

// ---------------- RoPE tables: cos/sin [2048][32] ----------------
__global__ void rope_tab_kernel(float* __restrict__ ct, float* __restrict__ st) {
  const int idx = blockIdx.x * 256 + threadIdx.x;   // 65536
  const int s = idx >> 5, i = idx & 31;
  const float ang = (float)s * exp2f(-10.0f * (float)i / 31.0f);  // (1/1024)^(i/31)
  float sv, cv;
  sincosf(ang, &sv, &cv);
  ct[idx] = cv;
  st[idx] = sv;
}

// ---------------- doc-start: qstart[i] = latest j<=i with ids[j]==EOT else 0 ----
__global__ __launch_bounds__(1024)
void docs_kernel(const int* __restrict__ ids, int* __restrict__ qstart) {
  __shared__ int a[2048], b2[2048];
  const int t = threadIdx.x;
  for (int i = t; i < 2048; i += 1024)
    a[i] = (ids[i] == EOT_ID) ? i : 0;
  __syncthreads();
  int* cur = a; int* nxt = b2;
  for (int off = 1; off < 2048; off <<= 1) {
    for (int i = t; i < 2048; i += 1024) {
      int v = cur[i];
      if (i >= off) { int u = cur[i - off]; v = (u > v) ? u : v; }
      nxt[i] = v;
    }
    __syncthreads();
    int* tmp = cur; cur = nxt; nxt = tmp;
  }
  for (int i = t; i < 2048; i += 1024) qstart[i] = cur[i];
}

// ---------------- weight transpose f32 [K][N] -> bf16 [N][K] ----------------
__global__ __launch_bounds__(256)
void wtrans_kernel(const float* __restrict__ in, unsigned short* __restrict__ out,
                   int K, int N) {
  __shared__ float tile[32][33];
  const int nb = N >> 5;
  const int k0 = (blockIdx.x / nb) << 5, n0 = (blockIdx.x % nb) << 5;
  const int tx = threadIdx.x & 31, ty = threadIdx.x >> 5;
#pragma unroll
  for (int p = 0; p < 4; p++)
    tile[ty + p * 8][tx] = in[(size_t)(k0 + ty + p * 8) * N + n0 + tx];
  __syncthreads();
#pragma unroll
  for (int p = 0; p < 4; p++)
    out[(size_t)(n0 + ty + p * 8) * K + k0 + tx] = f2bf(tile[tx][ty + p * 8]);
}

// ---------------- LayerNorm (optional residual mix) ----------------
template<bool MIX>
__global__ __launch_bounds__(256)
void ln_kernel(const float* __restrict__ x, const float* __restrict__ x0,
               const float* __restrict__ lam, const float* __restrict__ w,
               float* __restrict__ xm, unsigned short* __restrict__ xn) {
  __shared__ float red[8];
  const int row = blockIdx.x, t = threadIdx.x;
  const size_t base = (size_t)row << 10;
  float4 v = *(const float4*)(x + base + t * 4);
  if (MIX) {
    const float l0 = lam[0], l1 = lam[1];
    const float4 v0 = *(const float4*)(x0 + base + t * 4);
    v.x = l0 * v.x + l1 * v0.x;
    v.y = l0 * v.y + l1 * v0.y;
    v.z = l0 * v.z + l1 * v0.z;
    v.w = l0 * v.w + l1 * v0.w;
    *(float4*)(xm + base + t * 4) = v;
  }
  float s = v.x + v.y + v.z + v.w;
  float q = v.x * v.x + v.y * v.y + v.z * v.z + v.w * v.w;
#pragma unroll
  for (int off = 1; off < 64; off <<= 1) {
    s += __shfl_xor(s, off);
    q += __shfl_xor(q, off);
  }
  const int wid = t >> 6;
  if ((t & 63) == 0) { red[wid] = s; red[4 + wid] = q; }
  __syncthreads();
  s = red[0] + red[1] + red[2] + red[3];
  q = red[4] + red[5] + red[6] + red[7];
  const float mu = s * (1.0f / 1024.0f);
  const float var = q * (1.0f / 1024.0f) - mu * mu;
  const float rstd = rsqrtf(var + 1e-6f);
  const float4 wv = *(const float4*)(w + t * 4);
  ushort4 u;
  u.x = f2bf((v.x - mu) * rstd * wv.x);
  u.y = f2bf((v.y - mu) * rstd * wv.y);
  u.z = f2bf((v.z - mu) * rstd * wv.z);
  u.w = f2bf((v.w - mu) * rstd * wv.w);
  *(ushort4*)(xn + base + t * 4) = u;
}

// ---------------- GEMM: C[M][N] = A[M][K](bf16) * Bt[N][K](bf16)^T ----------------
// A operand: DIRECT global->register fragments (no LDS round-trip; each lane's
// frag is 16 contiguous bytes; a k-group's 16 lanes cover 16 rows x one 64B
// line -> fully-used cache lines). Register double-buffer afA/afB (named, rule
// #20). B operand: LDS double-buffer via global_load_lds, source-swizzled
// (0 bank conflicts). Exactly 6 VMEM ops/iter -> counted vmcnt(6) (T4).
// bm-slab XCD mapping. EPI 0: f32; 1: f32+residual; 2: relu^2 -> bf16.
template<int EPI, int BM>
__global__ __launch_bounds__(256, 4)
void gemm_bt(const unsigned short* __restrict__ A,
             const unsigned short* __restrict__ Bt,
             void* __restrict__ Cout,
             const float* __restrict__ res,
             int M, int N, int K) {
  __shared__ unsigned short Bs[2][128 * 32];
  const int t = threadIdx.x;
  const int wid = t >> 6;
  const int lane = t & 63;
  const int ln = lane & 15, kg = lane >> 4;
  const int nbm = M / BM;
  const int xcd = (int)blockIdx.x & 7, rr = (int)blockIdx.x >> 3;
  const int slab = nbm >> 3;
  const int bm = xcd * slab + (rr % slab);
  const int bn = rr / slab;
  const int m0 = bm * BM, n0 = bn << 7;
  const int wrow = (BM == 128) ? ((wid >> 1) * 64) : 0;       // wave row offset
  const int wcol = (BM == 128) ? ((wid & 1) * 64) : (wid * 32); // wave col offset
  constexpr int NJ = (BM == 128) ? 4 : 2;                     // n-frags per wave

  f32x4 acc[4][NJ] = {};

  const unsigned short* Ab = A + (size_t)(m0 + wrow + ln) * K + kg * 8;
  const unsigned short* Bbase = Bt + (size_t)n0 * K;

  auto STAGE_B = [&](int bb, int kt) {
#pragma unroll
    for (int p = 0; p < 2; p++) {
      const int e = t * 8 + p * 2048;
      const int r = e >> 5;
      const int cs = ((e >> 3) & 3) ^ ((r >> 1) & 3);
      GLOAD_LDS(Bbase + (size_t)r * K + kt + cs * 8, &Bs[bb][p * 2048 + wid * 512]);
    }
  };
  auto LOAD_A = [&](bf16x8* d, int kt) {
#pragma unroll
    for (int i = 0; i < 4; i++)
      d[i] = *(const bf16x8*)(Ab + (size_t)(i * 16) * K + kt);
  };
  auto COMPUTE = [&](const bf16x8* af, const unsigned short* bs) {
    bf16x8 bfr[NJ];
#pragma unroll
    for (int j = 0; j < NJ; j++) {
      const int rb = wcol + j * 16 + ln;
      bfr[j] = *(const bf16x8*)(&bs[rb * 32 + ((kg ^ ((rb >> 1) & 3)) << 3)]);
    }
#pragma unroll
    for (int i = 0; i < 4; i++)
#pragma unroll
      for (int j = 0; j < NJ; j++)
        acc[i][j] = __builtin_amdgcn_mfma_f32_16x16x32_bf16(af[i], bfr[j], acc[i][j], 0, 0, 0);
  };

  bf16x8 afA[4], afB[4];
  STAGE_B(0, 0);
  LOAD_A(afA, 0);
  const int nk = K >> 5;   // even (32 or 128)
  for (int ki = 0; ki < nk; ki += 2) {
    // even step: prefetch ki+1, compute ki
    STAGE_B(1, (ki + 1) << 5);
    LOAD_A(afB, (ki + 1) << 5);
    asm volatile("s_waitcnt vmcnt(6)" ::: "memory");
    __builtin_amdgcn_s_barrier();
    COMPUTE(afA, Bs[0]);
    __builtin_amdgcn_s_barrier();
    // odd step: prefetch ki+2, compute ki+1
    if (ki + 2 < nk) {
      STAGE_B(0, (ki + 2) << 5);
      LOAD_A(afA, (ki + 2) << 5);
      asm volatile("s_waitcnt vmcnt(6)" ::: "memory");
    } else {
      asm volatile("s_waitcnt vmcnt(0)" ::: "memory");
    }
    __builtin_amdgcn_s_barrier();
    COMPUTE(afB, Bs[1]);
    __builtin_amdgcn_s_barrier();
  }

#pragma unroll
  for (int i = 0; i < 4; i++) {
#pragma unroll
    for (int j = 0; j < NJ; j++) {
#pragma unroll
      for (int r = 0; r < 4; r++) {
        const int row = m0 + wrow + i * 16 + kg * 4 + r;
        const int col = n0 + wcol + j * 16 + ln;
        const size_t idx = (size_t)row * N + col;
        float v = acc[i][j][r];
        if (EPI == 0) {
          ((float*)Cout)[idx] = v;
        } else if (EPI == 1) {
          ((float*)Cout)[idx] = v + res[idx];
        } else {
          v = fmaxf(v, 0.0f);
          ((unsigned short*)Cout)[idx] = f2bf(v * v);
        }
      }
    }
  }
}

// ---------------- RoPE + RMSNorm + v-mix; writes Qh/Kh [b][s][h][hd], Vt [b][h][hd][s] ---
__global__ __launch_bounds__(256)
void rope_rms_kernel(const float* __restrict__ qkv,
                     const float* __restrict__ ct, const float* __restrict__ st,
                     const float* __restrict__ ve, const float* __restrict__ salam,
                     unsigned short* __restrict__ Qh, unsigned short* __restrict__ Kh,
                     unsigned short* __restrict__ Vt) {
  const int t = threadIdx.x;
  const int wid = t >> 6, i = t & 63;
  const int g = blockIdx.x * 4 + wid;      // (b,s,h)
  const int b = g >> 14;
  const int s = (g >> 3) & 2047;
  const int h = g & 7;
  const float* base = qkv + (size_t)(b * 2048 + s) * 3072 + h * 128;
  float c = 1.0f, sn = 0.0f;
  if (i < 32) { c = ct[s * 32 + i]; sn = st[s * 32 + i]; }
  const float q1 = base[i], q2 = base[64 + i];
  const float k1 = base[1024 + i], k2 = base[1024 + 64 + i];
  const float q1r = q1 * c + q2 * sn, q2r = q2 * c - q1 * sn;
  const float k1r = k1 * c + k2 * sn, k2r = k2 * c - k1 * sn;
  float sq = q1r * q1r + q2r * q2r;
  float sk = k1r * k1r + k2r * k2r;
#pragma unroll
  for (int off = 1; off < 64; off <<= 1) {
    sq += __shfl_xor(sq, off);
    sk += __shfl_xor(sk, off);
  }
  const float eps = 1.1920929e-7f;
  const float rq = rsqrtf(sq * (1.0f / 128.0f) + eps);
  const float rk = rsqrtf(sk * (1.0f / 128.0f) + eps);
  unsigned short* qp = Qh + (((size_t)(b * 2048 + s) * 8 + h) << 7);
  unsigned short* kp = Kh + (((size_t)(b * 2048 + s) * 8 + h) << 7);
  qp[i] = f2bf(q1r * rq); qp[64 + i] = f2bf(q2r * rq);
  kp[i] = f2bf(k1r * rk); kp[64 + i] = f2bf(k2r * rk);
  const float l0 = salam[0], l1 = salam[1];
  const float* vep = ve + (size_t)s * 1024 + h * 128;
  const float v1 = l0 * base[2048 + i] + l1 * vep[i];
  const float v2 = l0 * base[2048 + 64 + i] + l1 * vep[64 + i];
  unsigned short* vp = Vt + (((size_t)(b * 8 + h) * 128) << 11) + s;
  vp[(size_t)i << 11] = f2bf(v1);
  vp[(size_t)(64 + i) << 11] = f2bf(v2);
}

// ---------------- flash attention, doc-causal mask ----------------
// Swapped QK^T (mfma(K,Q) -> S^T): lane owns one q-row; scalar m/l; 2-shuffle
// reduces; defer-max; full-tile fast path; balanced pairing; 2-phase staging.
__global__ __launch_bounds__(256, 2)
void attn_kernel(const unsigned short* __restrict__ Qh,
                 const unsigned short* __restrict__ Kh,
                 const unsigned short* __restrict__ Vt,
                 const int* __restrict__ qstart,
                 unsigned short* __restrict__ Out) {
  __shared__ unsigned short Ks[2 * 64 * 128];   // [buf][key][hd] (chunk-swizzled)
  __shared__ unsigned short Vs[2 * 128 * 64];   // [buf][hd][key] (chunk-swizzled)
  __shared__ unsigned short Ps[4][16 * 72];     // per-wave P[q][key], stride 72

  const int blk = blockIdx.x;
  const int p_ = blk >> 4;
  const int qt = (p_ < 16) ? (31 - p_) : (p_ - 16);
  const int bh = blk & 15;
  const int b = bh >> 3, h = bh & 7;
  const int q0 = qt << 6;
  const int t = threadIdx.x;
  const int wid = t >> 6, lane = t & 63;
  const int ln = lane & 15, kg = lane >> 4;
  const int qrow = q0 + wid * 16;

  bf16x8 qf[4];   // Q[q=ln][k=s*32+kg*8+j]  (B-operand after swap)
  {
    const unsigned short* qp = Qh + (((size_t)(b * 2048 + qrow + ln) * 8 + h) << 7);
#pragma unroll
    for (int s = 0; s < 4; s++) qf[s] = *(const bf16x8*)(qp + s * 32 + kg * 8);
  }
  const int qid = qrow + ln;
  const int qs = qstart[qid];
  int qsmax = qs;
#pragma unroll
  for (int off = 1; off < 16; off <<= 1)
    qsmax = max(qsmax, __shfl_xor(qsmax, off));

  float m = -64.0f, l = 0.0f;   // scores bounded by |S*SC| <= ~22.2
  f32x4 o[8] = {};

  const int kt0 = qstart[q0] & ~63;
  const int kend = q0 + 64;
  const float SC = 0.12f * 1.4426950408889634f;  // scale * log2(e)

  auto STAGE = [&](int bb, int kt) {
#pragma unroll
    for (int r = 0; r < 4; r++) {
      const int e = t * 8 + r * 2048;
      const int row = e >> 7;
      const int scol = (((e >> 3) & 15) ^ (row & 7)) << 3;
      GLOAD_LDS(Kh + (((size_t)(b * 2048 + kt + row) * 8 + h) << 7) + scol,
                &Ks[bb * 8192 + r * 2048 + wid * 512]);
    }
#pragma unroll
    for (int r = 0; r < 4; r++) {
      const int e = t * 8 + r * 2048;
      const int row = e >> 6;
      const int scol = (((e >> 3) & 7) ^ (row & 7)) << 3;
      GLOAD_LDS(Vt + (((size_t)((b * 8 + h) * 128 + row)) << 11) + kt + scol,
                &Vs[bb * 8192 + r * 2048 + wid * 512]);
    }
  };

  STAGE(0, kt0);
  int cur = 0;

  for (int kt = kt0; kt < kend; kt += 64) {
    const bool hasnext = (kt + 64 < kend);
    if (hasnext) {
      STAGE(cur ^ 1, kt + 64);
      asm volatile("s_waitcnt vmcnt(8)" ::: "memory");
    } else {
      asm volatile("s_waitcnt vmcnt(0)" ::: "memory");
    }
    __builtin_amdgcn_s_barrier();

    const unsigned short* ksb = &Ks[cur * 8192];
    const unsigned short* vsb = &Vs[cur * 8192];

    // S^T[key][q]: sacc[nt] rows = keys nt*16 + kg*4+r, col = q = ln
    f32x4 sacc[4] = {};
#pragma unroll
    for (int nt = 0; nt < 4; nt++) {
#pragma unroll
      for (int s = 0; s < 4; s++) {
        bf16x8 kf = *(const bf16x8*)(&ksb[(nt * 16 + ln) * 128 + ((((s << 2) + kg) ^ (ln & 7)) << 3)]);
        sacc[nt] = __builtin_amdgcn_mfma_f32_16x16x32_bf16(kf, qf[s], sacc[nt], 0, 0, 0);
      }
    }

    const bool full = (kt + 64 <= qrow) && (kt >= qsmax);

    float p[4][4];
    float mx = -1e30f;
    if (full) {
#pragma unroll
      for (int nt = 0; nt < 4; nt++)
#pragma unroll
        for (int r = 0; r < 4; r++) {
          const float ts = sacc[nt][r] * SC;
          p[nt][r] = ts;
          mx = fmaxf(mx, ts);
        }
    } else {
#pragma unroll
      for (int nt = 0; nt < 4; nt++) {
#pragma unroll
        for (int r = 0; r < 4; r++) {
          const int key = kt + nt * 16 + kg * 4 + r;
          const bool valid = (key <= qid) && (key >= qs);
          const float ts = valid ? sacc[nt][r] * SC : -1e30f;
          p[nt][r] = ts;
          mx = fmaxf(mx, ts);
        }
      }
    }
    mx = fmaxf(mx, __shfl_xor(mx, 16));
    mx = fmaxf(mx, __shfl_xor(mx, 32));

    const bool dresc = __any(mx - m > 8.0f);
    if (dresc) {
      const float mn = fmaxf(m, mx);
      const float fac = exp2f(m - mn);
      m = mn;
      l *= fac;
      float ff[4];
#pragma unroll
      for (int r = 0; r < 4; r++) ff[r] = __shfl(fac, kg * 4 + r);
#pragma unroll
      for (int d = 0; d < 8; d++)
#pragma unroll
        for (int r = 0; r < 4; r++) o[d][r] *= ff[r];
    }

    float sum = 0.0f;
#pragma unroll
    for (int nt = 0; nt < 4; nt++)
#pragma unroll
      for (int r = 0; r < 4; r++) {
        const float pv = exp2f(p[nt][r] - m);   // masked (-1e30) underflows to 0
        p[nt][r] = pv;
        sum += pv;
      }
    sum += __shfl_xor(sum, 16);
    sum += __shfl_xor(sum, 32);
    l += sum;

    // P[q=ln][key]: 4x ds_write_b64 (r contiguous)
#pragma unroll
    for (int nt = 0; nt < 4; nt++) {
      u16x4 pk;
      pk[0] = f2bf(p[nt][0]); pk[1] = f2bf(p[nt][1]);
      pk[2] = f2bf(p[nt][2]); pk[3] = f2bf(p[nt][3]);
      *(u16x4*)(&Ps[wid][ln * 72 + nt * 16 + kg * 4]) = pk;
    }

#pragma unroll
    for (int ks = 0; ks < 2; ks++) {
      bf16x8 pf = *(const bf16x8*)(&Ps[wid][ln * 72 + ks * 32 + kg * 8]);
#pragma unroll
      for (int d = 0; d < 8; d++) {
        bf16x8 vf = *(const bf16x8*)(&vsb[(d * 16 + ln) * 64 + ((((ks << 2) + kg) ^ (ln & 7)) << 3)]);
        o[d] = __builtin_amdgcn_mfma_f32_16x16x32_bf16(pf, vf, o[d], 0, 0, 0);
      }
    }

    __builtin_amdgcn_s_barrier();
    cur ^= 1;
  }

  const float inv = 1.0f / l;
  float invr[4];
#pragma unroll
  for (int r = 0; r < 4; r++) invr[r] = __shfl(inv, kg * 4 + r);
#pragma unroll
  for (int r = 0; r < 4; r++) {
    const int q = qrow + kg * 4 + r;
#pragma unroll
    for (int d = 0; d < 8; d++) {
      Out[((size_t)(b * 2048 + q) << 10) + h * 128 + d * 16 + ln] = f2bf(o[d][r] * invr[r]);
    }
  }
}

// ---------------- launcher ----------------
extern "C" void kernel_launch(void* const* d_in, const int* in_sizes, int n_in,
                              void* d_out, int out_size, void* d_ws, size_t ws_size,
                              hipStream_t stream) {
  const float* x     = (const float*)d_in[0];
  const float* vemb  = (const float*)d_in[1];
  const float* x0    = (const float*)d_in[2];
  const float* lam   = (const float*)d_in[3];
  const float* slam  = (const float*)d_in[4];
  const float* ln1w  = (const float*)d_in[5];
  const float* ln2w  = (const float*)d_in[6];
  const float* wqkv  = (const float*)d_in[7];
  const float* wo    = (const float*)d_in[8];
  const float* wfc   = (const float*)d_in[9];
  const float* wproj = (const float*)d_in[10];
  const int*   ids   = (const int*)d_in[11];

  char* ws = (char*)d_ws;
  unsigned short* wqkvT  = (unsigned short*)(ws + 0);          //  6 MB
  unsigned short* woT    = (unsigned short*)(ws + 6291456);    //  2 MB
  unsigned short* wfcT   = (unsigned short*)(ws + 8388608);    //  8 MB
  unsigned short* wprojT = (unsigned short*)(ws + 16777216);   //  8 MB
  float*          xm     = (float*)(ws + 25165824);            // 16 MB
  float*          qkv    = (float*)(ws + 41943040);            // 48 MB
  unsigned short* hbuf   = (unsigned short*)(ws + 41943040);   // reuse (32 MB)
  unsigned short* xn1    = (unsigned short*)(ws + 92274688);   //  8 MB
  unsigned short* ao     = (unsigned short*)(ws + 92274688);   // reuse
  unsigned short* qh     = (unsigned short*)(ws + 100663296);  //  8 MB
  unsigned short* xn2    = (unsigned short*)(ws + 100663296);  // reuse
  unsigned short* kh     = (unsigned short*)(ws + 109051904);  //  8 MB
  unsigned short* vt     = (unsigned short*)(ws + 117440512);  //  8 MB
  float*          x2     = (float*)(ws + 109051904);           // reuse kh+vt (16 MB)
  float*          ctab   = (float*)(ws + 125829120);
  float*          stab   = (float*)(ws + 126091264);
  int*            qstart = (int*)(ws + 126353408);

  rope_tab_kernel<<<dim3(256), dim3(256), 0, stream>>>(ctab, stab);
  docs_kernel<<<dim3(1), dim3(1024), 0, stream>>>(ids, qstart);
  wtrans_kernel<<<dim3(32 * 96), dim3(256), 0, stream>>>(wqkv, wqkvT, 1024, 3072);
  wtrans_kernel<<<dim3(32 * 32), dim3(256), 0, stream>>>(wo, woT, 1024, 1024);
  wtrans_kernel<<<dim3(32 * 128), dim3(256), 0, stream>>>(wfc, wfcT, 1024, 4096);
  wtrans_kernel<<<dim3(128 * 32), dim3(256), 0, stream>>>(wproj, wprojT, 4096, 1024);

  ln_kernel<true><<<dim3(4096), dim3(256), 0, stream>>>(x, x0, lam, ln1w, xm, xn1);
  gemm_bt<0, 128><<<dim3(32 * 24), dim3(256), 0, stream>>>(xn1, wqkvT, (void*)qkv,
                                                           (const float*)nullptr, 4096, 3072, 1024);
  rope_rms_kernel<<<dim3(8192), dim3(256), 0, stream>>>(qkv, ctab, stab, vemb, slam, qh, kh, vt);
  attn_kernel<<<dim3(512), dim3(256), 0, stream>>>(qh, kh, vt, qstart, ao);
  gemm_bt<1, 64><<<dim3(64 * 8), dim3(256), 0, stream>>>(ao, woT, (void*)x2, xm, 4096, 1024, 1024);
  ln_kernel<false><<<dim3(4096), dim3(256), 0, stream>>>(x2, (const float*)nullptr,
                                                         (const float*)nullptr, ln2w,
                                                         (float*)nullptr, xn2);
  gemm_bt<2, 128><<<dim3(32 * 32), dim3(256), 0, stream>>>(xn2, wfcT, (void*)hbuf,
                                                           (const float*)nullptr, 4096, 4096, 1024);
  gemm_bt<1, 64><<<dim3(64 * 8), dim3(256), 0, stream>>>(hbuf, wprojT, d_out, x2, 4096, 1024, 4096);
}

// Round 8
// 278.982 us; speedup vs baseline: 1.6919x; 1.6919x over previous
//
#include <hip/hip_runtime.h>

#define EOT_ID 50256

typedef __attribute__((ext_vector_type(8))) short bf16x8;
typedef __attribute__((ext_vector_type(4))) float f32x4;
typedef __attribute__((ext_vector_type(4))) unsigned short u16x4;

#define GLOAD_LDS(g, l)                                                        \
  __builtin_amdgcn_global_load_lds(                                            \
      (const __attribute__((address_space(1))) unsigned int*)(g),              \
      (__attribute__((address_space(3))) unsigned int*)(l), 16, 0, 0)

__device__ __forceinline__ unsigned short f2bf(float f) {
  union { float f; unsigned int u; } v; v.f = f;
  unsigned int r = v.u + 0x7FFFu + ((v.u >> 16) & 1u);
  return (unsigned short)(r >> 16);
}
__device__ __forceinline__ float bf2f(unsigned short b) {
  union { unsigned int u; float f; } v; v.u = ((unsigned int)b) << 16;
  return v.f;
}

// ---------------- RoPE tables: cos/sin [2048][32] ----------------
__global__ void rope_tab_kernel(float* __restrict__ ct, float* __restrict__ st) {
  const int idx = blockIdx.x * 256 + threadIdx.x;   // 65536
  const int s = idx >> 5, i = idx & 31;
  const float ang = (float)s * exp2f(-10.0f * (float)i / 31.0f);  // (1/1024)^(i/31)
  float sv, cv;
  sincosf(ang, &sv, &cv);
  ct[idx] = cv;
  st[idx] = sv;
}

// ---------------- doc-start: qstart[i] = latest j<=i with ids[j]==EOT else 0 ----
__global__ __launch_bounds__(1024)
void docs_kernel(const int* __restrict__ ids, int* __restrict__ qstart) {
  __shared__ int a[2048], b2[2048];
  const int t = threadIdx.x;
  for (int i = t; i < 2048; i += 1024)
    a[i] = (ids[i] == EOT_ID) ? i : 0;
  __syncthreads();
  int* cur = a; int* nxt = b2;
  for (int off = 1; off < 2048; off <<= 1) {
    for (int i = t; i < 2048; i += 1024) {
      int v = cur[i];
      if (i >= off) { int u = cur[i - off]; v = (u > v) ? u : v; }
      nxt[i] = v;
    }
    __syncthreads();
    int* tmp = cur; cur = nxt; nxt = tmp;
  }
  for (int i = t; i < 2048; i += 1024) qstart[i] = cur[i];
}

// ---------------- weight transpose f32 [K][N] -> bf16 [N][K] ----------------
__global__ __launch_bounds__(256)
void wtrans_kernel(const float* __restrict__ in, unsigned short* __restrict__ out,
                   int K, int N) {
  __shared__ float tile[32][33];
  const int nb = N >> 5;
  const int k0 = (blockIdx.x / nb) << 5, n0 = (blockIdx.x % nb) << 5;
  const int tx = threadIdx.x & 31, ty = threadIdx.x >> 5;
#pragma unroll
  for (int p = 0; p < 4; p++)
    tile[ty + p * 8][tx] = in[(size_t)(k0 + ty + p * 8) * N + n0 + tx];
  __syncthreads();
#pragma unroll
  for (int p = 0; p < 4; p++)
    out[(size_t)(n0 + ty + p * 8) * K + k0 + tx] = f2bf(tile[tx][ty + p * 8]);
}

// ---------------- LayerNorm (optional residual mix) ----------------
template<bool MIX>
__global__ __launch_bounds__(256)
void ln_kernel(const float* __restrict__ x, const float* __restrict__ x0,
               const float* __restrict__ lam, const float* __restrict__ w,
               float* __restrict__ xm, unsigned short* __restrict__ xn) {
  __shared__ float red[8];
  const int row = blockIdx.x, t = threadIdx.x;
  const size_t base = (size_t)row << 10;
  float4 v = *(const float4*)(x + base + t * 4);
  if (MIX) {
    const float l0 = lam[0], l1 = lam[1];
    const float4 v0 = *(const float4*)(x0 + base + t * 4);
    v.x = l0 * v.x + l1 * v0.x;
    v.y = l0 * v.y + l1 * v0.y;
    v.z = l0 * v.z + l1 * v0.z;
    v.w = l0 * v.w + l1 * v0.w;
    *(float4*)(xm + base + t * 4) = v;
  }
  float s = v.x + v.y + v.z + v.w;
  float q = v.x * v.x + v.y * v.y + v.z * v.z + v.w * v.w;
#pragma unroll
  for (int off = 1; off < 64; off <<= 1) {
    s += __shfl_xor(s, off);
    q += __shfl_xor(q, off);
  }
  const int wid = t >> 6;
  if ((t & 63) == 0) { red[wid] = s; red[4 + wid] = q; }
  __syncthreads();
  s = red[0] + red[1] + red[2] + red[3];
  q = red[4] + red[5] + red[6] + red[7];
  const float mu = s * (1.0f / 1024.0f);
  const float var = q * (1.0f / 1024.0f) - mu * mu;
  const float rstd = rsqrtf(var + 1e-6f);
  const float4 wv = *(const float4*)(w + t * 4);
  ushort4 u;
  u.x = f2bf((v.x - mu) * rstd * wv.x);
  u.y = f2bf((v.y - mu) * rstd * wv.y);
  u.z = f2bf((v.z - mu) * rstd * wv.z);
  u.w = f2bf((v.w - mu) * rstd * wv.w);
  *(ushort4*)(xn + base + t * 4) = u;
}

// ---------------- GEMM: C[M][N] = A[M][K](bf16) * Bt[N][K](bf16)^T ----------------
// 2-phase pipelined LDS double-buffer via global_load_lds (round-5 structure,
// the known-good one: fully-coalesced staging, counted vmcnt, source-swizzled).
// BK=32 swizzle: chunk ^ ((row>>1)&3); BK=64 swizzle: chunk ^ (row&7) (rows are
// 128B = all 32 banks; XOR by row spreads the 16-lane column read -> 2-way).
// BK=64 halves the barrier/wait count for the K-deep BM=64 shapes.
// EPI 0: f32; 1: f32 + residual; 2: relu^2 -> bf16; 3: bf16.
template<int EPI, int BM, int BK>
__global__ __launch_bounds__(256, 4)
void gemm_bt(const unsigned short* __restrict__ A,
             const unsigned short* __restrict__ Bt,
             void* __restrict__ Cout,
             const float* __restrict__ res,
             int M, int N, int K) {
  __shared__ unsigned short As[2][BM * BK];
  __shared__ unsigned short Bs[2][128 * BK];
  const int t = threadIdx.x;
  const int wid = t >> 6;
  const int lane = t & 63;
  const int ln = lane & 15, kg = lane >> 4;
  const int nbm = M / BM;
  const int xcd = (int)blockIdx.x & 7, rr = (int)blockIdx.x >> 3;
  const int slab = nbm >> 3;
  const int bm = xcd * slab + (rr % slab);
  const int bn = rr / slab;
  const int m0 = bm * BM, n0 = bn << 7;
  const int wrow = (BM == 128) ? ((wid >> 1) * 64) : 0;
  const int wcol = (BM == 128) ? ((wid & 1) * 64) : (wid * 32);
  constexpr int NJ = (BM == 128) ? 4 : 2;          // n-frags per wave
  constexpr int LA = BM * BK / 2048;               // A stage rounds
  constexpr int LB = 128 * BK / 2048;              // B stage rounds
  constexpr int KC = BK / 32;                      // k-chunks per tile

  f32x4 acc[4][NJ] = {};

  const unsigned short* Abase = A + (size_t)m0 * K;
  const unsigned short* Bbase = Bt + (size_t)n0 * K;

  // swizzle: chunk index (16B units) XORed with row bits (involution)
  auto swz = [&](int row, int chunk) -> int {
    if constexpr (BK == 32) return chunk ^ ((row >> 1) & 3);
    else                    return chunk ^ (row & 7);
  };

  auto STAGE = [&](int bb, int kt) {
#pragma unroll
    for (int p = 0; p < LA; p++) {
      const int e = t * 8 + p * 2048;
      const int r = e / BK;
      const int cs = swz(r, (e >> 3) & (BK / 8 - 1));
      GLOAD_LDS(Abase + (size_t)r * K + kt + cs * 8, &As[bb][p * 2048 + wid * 512]);
    }
#pragma unroll
    for (int p = 0; p < LB; p++) {
      const int e = t * 8 + p * 2048;
      const int r = e / BK;
      const int cs = swz(r, (e >> 3) & (BK / 8 - 1));
      GLOAD_LDS(Bbase + (size_t)r * K + kt + cs * 8, &Bs[bb][p * 2048 + wid * 512]);
    }
  };

  STAGE(0, 0);
  int cur = 0;
  const int nk = K / BK;
  for (int ki = 0; ki < nk; ki++) {
    if (ki + 1 < nk) {
      STAGE(cur ^ 1, (ki + 1) * BK);
      if constexpr (LA + LB == 4)
        asm volatile("s_waitcnt vmcnt(4)" ::: "memory");
      else
        asm volatile("s_waitcnt vmcnt(6)" ::: "memory");
    } else {
      asm volatile("s_waitcnt vmcnt(0)" ::: "memory");
    }
    __builtin_amdgcn_s_barrier();

#pragma unroll
    for (int c = 0; c < KC; c++) {
      bf16x8 af[4], bfr[NJ];
#pragma unroll
      for (int i = 0; i < 4; i++) {
        const int ra = wrow + i * 16 + ln;
        af[i] = *(const bf16x8*)(&As[cur][ra * BK + swz(ra, c * 4 + kg) * 8]);
      }
#pragma unroll
      for (int j = 0; j < NJ; j++) {
        const int rb = wcol + j * 16 + ln;
        bfr[j] = *(const bf16x8*)(&Bs[cur][rb * BK + swz(rb, c * 4 + kg) * 8]);
      }
#pragma unroll
      for (int i = 0; i < 4; i++)
#pragma unroll
        for (int j = 0; j < NJ; j++)
          acc[i][j] = __builtin_amdgcn_mfma_f32_16x16x32_bf16(af[i], bfr[j], acc[i][j], 0, 0, 0);
    }

    __builtin_amdgcn_s_barrier();
    cur ^= 1;
  }

#pragma unroll
  for (int i = 0; i < 4; i++) {
#pragma unroll
    for (int j = 0; j < NJ; j++) {
#pragma unroll
      for (int r = 0; r < 4; r++) {
        const int row = m0 + wrow + i * 16 + kg * 4 + r;
        const int col = n0 + wcol + j * 16 + ln;
        const size_t idx = (size_t)row * N + col;
        float v = acc[i][j][r];
        if (EPI == 0) {
          ((float*)Cout)[idx] = v;
        } else if (EPI == 1) {
          ((float*)Cout)[idx] = v + res[idx];
        } else if (EPI == 2) {
          v = fmaxf(v, 0.0f);
          ((unsigned short*)Cout)[idx] = f2bf(v * v);
        } else {
          ((unsigned short*)Cout)[idx] = f2bf(v);
        }
      }
    }
  }
}

// ---------------- RoPE + RMSNorm + v-mix (qkv in bf16) ----------------
// writes Qh/Kh [b][s][h][hd], Vt [b][h][hd][s]
__global__ __launch_bounds__(256)
void rope_rms_kernel(const unsigned short* __restrict__ qkv,
                     const float* __restrict__ ct, const float* __restrict__ st,
                     const float* __restrict__ ve, const float* __restrict__ salam,
                     unsigned short* __restrict__ Qh, unsigned short* __restrict__ Kh,
                     unsigned short* __restrict__ Vt) {
  const int t = threadIdx.x;
  const int wid = t >> 6, i = t & 63;
  const int g = blockIdx.x * 4 + wid;      // (b,s,h)
  const int b = g >> 14;
  const int s = (g >> 3) & 2047;
  const int h = g & 7;
  const unsigned short* base = qkv + (size_t)(b * 2048 + s) * 3072 + h * 128;
  float c = 1.0f, sn = 0.0f;
  if (i < 32) { c = ct[s * 32 + i]; sn = st[s * 32 + i]; }
  const float q1 = bf2f(base[i]), q2 = bf2f(base[64 + i]);
  const float k1 = bf2f(base[1024 + i]), k2 = bf2f(base[1024 + 64 + i]);
  const float q1r = q1 * c + q2 * sn, q2r = q2 * c - q1 * sn;
  const float k1r = k1 * c + k2 * sn, k2r = k2 * c - k1 * sn;
  float sq = q1r * q1r + q2r * q2r;
  float sk = k1r * k1r + k2r * k2r;
#pragma unroll
  for (int off = 1; off < 64; off <<= 1) {
    sq += __shfl_xor(sq, off);
    sk += __shfl_xor(sk, off);
  }
  const float eps = 1.1920929e-7f;
  const float rq = rsqrtf(sq * (1.0f / 128.0f) + eps);
  const float rk = rsqrtf(sk * (1.0f / 128.0f) + eps);
  unsigned short* qp = Qh + (((size_t)(b * 2048 + s) * 8 + h) << 7);
  unsigned short* kp = Kh + (((size_t)(b * 2048 + s) * 8 + h) << 7);
  qp[i] = f2bf(q1r * rq); qp[64 + i] = f2bf(q2r * rq);
  kp[i] = f2bf(k1r * rk); kp[64 + i] = f2bf(k2r * rk);
  const float l0 = salam[0], l1 = salam[1];
  const float* vep = ve + (size_t)s * 1024 + h * 128;
  const float v1 = l0 * bf2f(base[2048 + i]) + l1 * vep[i];
  const float v2 = l0 * bf2f(base[2048 + 64 + i]) + l1 * vep[64 + i];
  unsigned short* vp = Vt + (((size_t)(b * 8 + h) * 128) << 11) + s;
  vp[(size_t)i << 11] = f2bf(v1);
  vp[(size_t)(64 + i) << 11] = f2bf(v2);
}

// ---------------- flash attention, doc-causal mask ----------------
// Swapped QK^T (mfma(K,Q) -> S^T): lane owns one q-row; scalar m/l; 2-shuffle
// reduces; defer-max; full-tile fast path; balanced pairing; 2-phase staging.
__global__ __launch_bounds__(256, 2)
void attn_kernel(const unsigned short* __restrict__ Qh,
                 const unsigned short* __restrict__ Kh,
                 const unsigned short* __restrict__ Vt,
                 const int* __restrict__ qstart,
                 unsigned short* __restrict__ Out) {
  __shared__ unsigned short Ks[2 * 64 * 128];   // [buf][key][hd] (chunk-swizzled)
  __shared__ unsigned short Vs[2 * 128 * 64];   // [buf][hd][key] (chunk-swizzled)
  __shared__ unsigned short Ps[4][16 * 72];     // per-wave P[q][key], stride 72

  const int blk = blockIdx.x;
  const int p_ = blk >> 4;
  const int qt = (p_ < 16) ? (31 - p_) : (p_ - 16);
  const int bh = blk & 15;
  const int b = bh >> 3, h = bh & 7;
  const int q0 = qt << 6;
  const int t = threadIdx.x;
  const int wid = t >> 6, lane = t & 63;
  const int ln = lane & 15, kg = lane >> 4;
  const int qrow = q0 + wid * 16;

  bf16x8 qf[4];   // Q[q=ln][k=s*32+kg*8+j]  (B-operand after swap)
  {
    const unsigned short* qp = Qh + (((size_t)(b * 2048 + qrow + ln) * 8 + h) << 7);
#pragma unroll
    for (int s = 0; s < 4; s++) qf[s] = *(const bf16x8*)(qp + s * 32 + kg * 8);
  }
  const int qid = qrow + ln;
  const int qs = qstart[qid];
  int qsmax = qs;
#pragma unroll
  for (int off = 1; off < 16; off <<= 1)
    qsmax = max(qsmax, __shfl_xor(qsmax, off));

  float m = -64.0f, l = 0.0f;   // scores bounded by |S*SC| <= ~22.2
  f32x4 o[8] = {};

  const int kt0 = qstart[q0] & ~63;
  const int kend = q0 + 64;
  const float SC = 0.12f * 1.4426950408889634f;  // scale * log2(e)

  auto STAGE = [&](int bb, int kt) {
#pragma unroll
    for (int r = 0; r < 4; r++) {
      const int e = t * 8 + r * 2048;
      const int row = e >> 7;
      const int scol = (((e >> 3) & 15) ^ (row & 7)) << 3;
      GLOAD_LDS(Kh + (((size_t)(b * 2048 + kt + row) * 8 + h) << 7) + scol,
                &Ks[bb * 8192 + r * 2048 + wid * 512]);
    }
#pragma unroll
    for (int r = 0; r < 4; r++) {
      const int e = t * 8 + r * 2048;
      const int row = e >> 6;
      const int scol = (((e >> 3) & 7) ^ (row & 7)) << 3;
      GLOAD_LDS(Vt + (((size_t)((b * 8 + h) * 128 + row)) << 11) + kt + scol,
                &Vs[bb * 8192 + r * 2048 + wid * 512]);
    }
  };

  STAGE(0, kt0);
  int cur = 0;

  for (int kt = kt0; kt < kend; kt += 64) {
    const bool hasnext = (kt + 64 < kend);
    if (hasnext) {
      STAGE(cur ^ 1, kt + 64);
      asm volatile("s_waitcnt vmcnt(8)" ::: "memory");
    } else {
      asm volatile("s_waitcnt vmcnt(0)" ::: "memory");
    }
    __builtin_amdgcn_s_barrier();

    const unsigned short* ksb = &Ks[cur * 8192];
    const unsigned short* vsb = &Vs[cur * 8192];

    // S^T[key][q]: sacc[nt] rows = keys nt*16 + kg*4+r, col = q = ln
    f32x4 sacc[4] = {};
#pragma unroll
    for (int nt = 0; nt < 4; nt++) {
#pragma unroll
      for (int s = 0; s < 4; s++) {
        bf16x8 kf = *(const bf16x8*)(&ksb[(nt * 16 + ln) * 128 + ((((s << 2) + kg) ^ (ln & 7)) << 3)]);
        sacc[nt] = __builtin_amdgcn_mfma_f32_16x16x32_bf16(kf, qf[s], sacc[nt], 0, 0, 0);
      }
    }

    const bool full = (kt + 64 <= qrow) && (kt >= qsmax);

    float p[4][4];
    float mx = -1e30f;
    if (full) {
#pragma unroll
      for (int nt = 0; nt < 4; nt++)
#pragma unroll
        for (int r = 0; r < 4; r++) {
          const float ts = sacc[nt][r] * SC;
          p[nt][r] = ts;
          mx = fmaxf(mx, ts);
        }
    } else {
#pragma unroll
      for (int nt = 0; nt < 4; nt++) {
#pragma unroll
        for (int r = 0; r < 4; r++) {
          const int key = kt + nt * 16 + kg * 4 + r;
          const bool valid = (key <= qid) && (key >= qs);
          const float ts = valid ? sacc[nt][r] * SC : -1e30f;
          p[nt][r] = ts;
          mx = fmaxf(mx, ts);
        }
      }
    }
    mx = fmaxf(mx, __shfl_xor(mx, 16));
    mx = fmaxf(mx, __shfl_xor(mx, 32));

    const bool dresc = __any(mx - m > 8.0f);
    if (dresc) {
      const float mn = fmaxf(m, mx);
      const float fac = exp2f(m - mn);
      m = mn;
      l *= fac;
      float ff[4];
#pragma unroll
      for (int r = 0; r < 4; r++) ff[r] = __shfl(fac, kg * 4 + r);
#pragma unroll
      for (int d = 0; d < 8; d++)
#pragma unroll
        for (int r = 0; r < 4; r++) o[d][r] *= ff[r];
    }

    float sum = 0.0f;
#pragma unroll
    for (int nt = 0; nt < 4; nt++)
#pragma unroll
      for (int r = 0; r < 4; r++) {
        const float pv = exp2f(p[nt][r] - m);   // masked (-1e30) underflows to 0
        p[nt][r] = pv;
        sum += pv;
      }
    sum += __shfl_xor(sum, 16);
    sum += __shfl_xor(sum, 32);
    l += sum;

    // P[q=ln][key]: 4x ds_write_b64 (r contiguous)
#pragma unroll
    for (int nt = 0; nt < 4; nt++) {
      u16x4 pk;
      pk[0] = f2bf(p[nt][0]); pk[1] = f2bf(p[nt][1]);
      pk[2] = f2bf(p[nt][2]); pk[3] = f2bf(p[nt][3]);
      *(u16x4*)(&Ps[wid][ln * 72 + nt * 16 + kg * 4]) = pk;
    }

#pragma unroll
    for (int ks = 0; ks < 2; ks++) {
      bf16x8 pf = *(const bf16x8*)(&Ps[wid][ln * 72 + ks * 32 + kg * 8]);
#pragma unroll
      for (int d = 0; d < 8; d++) {
        bf16x8 vf = *(const bf16x8*)(&vsb[(d * 16 + ln) * 64 + ((((ks << 2) + kg) ^ (ln & 7)) << 3)]);
        o[d] = __builtin_amdgcn_mfma_f32_16x16x32_bf16(pf, vf, o[d], 0, 0, 0);
      }
    }

    __builtin_amdgcn_s_barrier();
    cur ^= 1;
  }

  const float inv = 1.0f / l;
  float invr[4];
#pragma unroll
  for (int r = 0; r < 4; r++) invr[r] = __shfl(inv, kg * 4 + r);
#pragma unroll
  for (int r = 0; r < 4; r++) {
    const int q = qrow + kg * 4 + r;
#pragma unroll
    for (int d = 0; d < 8; d++) {
      Out[((size_t)(b * 2048 + q) << 10) + h * 128 + d * 16 + ln] = f2bf(o[d][r] * invr[r]);
    }
  }
}

// ---------------- launcher ----------------
extern "C" void kernel_launch(void* const* d_in, const int* in_sizes, int n_in,
                              void* d_out, int out_size, void* d_ws, size_t ws_size,
                              hipStream_t stream) {
  const float* x     = (const float*)d_in[0];
  const float* vemb  = (const float*)d_in[1];
  const float* x0    = (const float*)d_in[2];
  const float* lam   = (const float*)d_in[3];
  const float* slam  = (const float*)d_in[4];
  const float* ln1w  = (const float*)d_in[5];
  const float* ln2w  = (const float*)d_in[6];
  const float* wqkv  = (const float*)d_in[7];
  const float* wo    = (const float*)d_in[8];
  const float* wfc   = (const float*)d_in[9];
  const float* wproj = (const float*)d_in[10];
  const int*   ids   = (const int*)d_in[11];

  char* ws = (char*)d_ws;
  unsigned short* wqkvT  = (unsigned short*)(ws + 0);          //  6 MB
  unsigned short* woT    = (unsigned short*)(ws + 6291456);    //  2 MB
  unsigned short* wfcT   = (unsigned short*)(ws + 8388608);    //  8 MB
  unsigned short* wprojT = (unsigned short*)(ws + 16777216);   //  8 MB
  float*          xm     = (float*)(ws + 25165824);            // 16 MB
  unsigned short* qkv    = (unsigned short*)(ws + 41943040);   // 24 MB (bf16)
  unsigned short* hbuf   = (unsigned short*)(ws + 41943040);   // reuse (32 MB)
  unsigned short* xn1    = (unsigned short*)(ws + 92274688);   //  8 MB
  unsigned short* ao     = (unsigned short*)(ws + 92274688);   // reuse
  unsigned short* qh     = (unsigned short*)(ws + 100663296);  //  8 MB
  unsigned short* xn2    = (unsigned short*)(ws + 100663296);  // reuse
  unsigned short* kh     = (unsigned short*)(ws + 109051904);  //  8 MB
  unsigned short* vt     = (unsigned short*)(ws + 117440512);  //  8 MB
  float*          x2     = (float*)(ws + 109051904);           // reuse kh+vt (16 MB)
  float*          ctab   = (float*)(ws + 125829120);
  float*          stab   = (float*)(ws + 126091264);
  int*            qstart = (int*)(ws + 126353408);

  rope_tab_kernel<<<dim3(256), dim3(256), 0, stream>>>(ctab, stab);
  docs_kernel<<<dim3(1), dim3(1024), 0, stream>>>(ids, qstart);
  wtrans_kernel<<<dim3(32 * 96), dim3(256), 0, stream>>>(wqkv, wqkvT, 1024, 3072);
  wtrans_kernel<<<dim3(32 * 32), dim3(256), 0, stream>>>(wo, woT, 1024, 1024);
  wtrans_kernel<<<dim3(32 * 128), dim3(256), 0, stream>>>(wfc, wfcT, 1024, 4096);
  wtrans_kernel<<<dim3(128 * 32), dim3(256), 0, stream>>>(wproj, wprojT, 4096, 1024);

  ln_kernel<true><<<dim3(4096), dim3(256), 0, stream>>>(x, x0, lam, ln1w, xm, xn1);
  gemm_bt<3, 128, 32><<<dim3(32 * 24), dim3(256), 0, stream>>>(xn1, wqkvT, (void*)qkv,
                                                               (const float*)nullptr, 4096, 3072, 1024);
  rope_rms_kernel<<<dim3(8192), dim3(256), 0, stream>>>(qkv, ctab, stab, vemb, slam, qh, kh, vt);
  attn_kernel<<<dim3(512), dim3(256), 0, stream>>>(qh, kh, vt, qstart, ao);
  gemm_bt<1, 64, 64><<<dim3(64 * 8), dim3(256), 0, stream>>>(ao, woT, (void*)x2, xm, 4096, 1024, 1024);
  ln_kernel<false><<<dim3(4096), dim3(256), 0, stream>>>(x2, (const float*)nullptr,
                                                         (const float*)nullptr, ln2w,
                                                         (float*)nullptr, xn2);
  gemm_bt<2, 128, 32><<<dim3(32 * 32), dim3(256), 0, stream>>>(xn2, wfcT, (void*)hbuf,
                                                               (const float*)nullptr, 4096, 4096, 1024);
  gemm_bt<1, 64, 64><<<dim3(64 * 8), dim3(256), 0, stream>>>(hbuf, wprojT, d_out, x2, 4096, 1024, 4096);
}